// Round 3
// baseline (819.268 us; speedup 1.0000x reference)
//
#include <hip/hip_runtime.h>
#include <hip/hip_bf16.h>
#include <math.h>

// PsiForesight fused pipeline for MI355X (gfx950).
// B=4, T=16, A=512, Z=512, E=64, H=8, HD=64, NF=6. Rows = B*T*A = 32768.
//
// R3: interface dtype corrected to FLOAT32 (per reference setup_inputs).
// Internal compute: bf16 MFMA (16x16x32), f32 accumulate. Weights are
// transposed+converted f32->bf16; activations converted once per stage.

typedef __bf16 bf16x8 __attribute__((ext_vector_type(8)));
typedef float f32x4 __attribute__((ext_vector_type(4)));

#define ROWS 32768
#define ZDIM 512

__device__ __forceinline__ float gelu_f(float x) {
  return 0.5f * x * (1.0f + erff(x * 0.70710678118654752f));
}

// ---------------- f32 -> bf16 transpose: out[C][R] = in[R][C] --------------
__global__ void transpose_f32_bf16(const float* __restrict__ in,
                                   __bf16* __restrict__ out, int R, int C) {
  __shared__ float tile[32][33];
  int c0 = blockIdx.x * 32, r0 = blockIdx.y * 32;
#pragma unroll
  for (int i = 0; i < 32; i += 8)
    tile[i + threadIdx.y][threadIdx.x] =
        in[(size_t)(r0 + i + threadIdx.y) * C + c0 + threadIdx.x];
  __syncthreads();
#pragma unroll
  for (int i = 0; i < 32; i += 8)
    out[(size_t)(c0 + i + threadIdx.y) * R + r0 + threadIdx.x] =
        (__bf16)tile[threadIdx.x][i + threadIdx.y];
}

// ---------------- f32 -> bf16 convert (n % 1024 == 0) ----------------------
__global__ void cvt_f32_bf16(const float* __restrict__ in,
                             __bf16* __restrict__ out) {
  int i = (blockIdx.x * 256 + threadIdx.x) * 4;
  float4 v = *(const float4*)(in + i);
  out[i + 0] = (__bf16)v.x;
  out[i + 1] = (__bf16)v.y;
  out[i + 2] = (__bf16)v.z;
  out[i + 3] = (__bf16)v.w;
}

// ---------------- LayerNorm rows (optionally x = a + gate*b) ----------------
// xa: f32 input rows. xb: bf16 addend (GATED). out: bf16 LN result.
// raw: bf16 copy of xa (EMIT_RAW, pre-LN) for the concat-A gemm.
template <bool GATED, bool EMIT_RAW>
__global__ __launch_bounds__(256) void ln_kernel(
    const float* __restrict__ xa, const __bf16* __restrict__ xb,
    const float* __restrict__ gate, const float* __restrict__ gamma,
    const float* __restrict__ beta, __bf16* __restrict__ out,
    __bf16* __restrict__ raw) {
  int row = blockIdx.x;
  int tid = threadIdx.x;
  int i0 = tid * 2;
  const float* ra = xa + (size_t)row * ZDIM;
  float x0 = ra[i0], x1 = ra[i0 + 1];
  if (EMIT_RAW) {
    raw[(size_t)row * ZDIM + i0] = (__bf16)x0;
    raw[(size_t)row * ZDIM + i0 + 1] = (__bf16)x1;
  }
  if (GATED) {
    float gv = gate[row];
    const __bf16* rb = xb + (size_t)row * ZDIM;
    x0 += gv * (float)rb[i0];
    x1 += gv * (float)rb[i0 + 1];
  }
  float s = x0 + x1, s2 = x0 * x0 + x1 * x1;
#pragma unroll
  for (int off = 32; off > 0; off >>= 1) {
    s += __shfl_down(s, off);
    s2 += __shfl_down(s2, off);
  }
  __shared__ float red[8];
  int wave = tid >> 6, lane = tid & 63;
  if (lane == 0) { red[wave] = s; red[4 + wave] = s2; }
  __syncthreads();
  float ts = red[0] + red[1] + red[2] + red[3];
  float ts2 = red[4] + red[5] + red[6] + red[7];
  float mean = ts * (1.0f / ZDIM);
  float var = ts2 * (1.0f / ZDIM) - mean * mean;
  float rstd = rsqrtf(var + 1e-5f);
  float y0 = (x0 - mean) * rstd * gamma[i0] + beta[i0];
  float y1 = (x1 - mean) * rstd * gamma[i0 + 1] + beta[i0 + 1];
  out[(size_t)row * ZDIM + i0] = (__bf16)y0;
  out[(size_t)row * ZDIM + i0 + 1] = (__bf16)y1;
}

// ---------------- edge features: e[bt][512] (all f32) ----------------------
__global__ void edge_kernel(const float* __restrict__ actions,
                            const float* __restrict__ W_edge,
                            const float* __restrict__ b_edge,
                            const float* __restrict__ We,
                            float* __restrict__ e) {
  int bt = blockIdx.x;   // 0..63
  int tid = threadIdx.x; // 0..63
  float dx = actions[bt * 4 + 0];
  float dy = actions[bt * 4 + 1];
  float th = actions[bt * 4 + 2];
  float feats[38];
  feats[0] = sinf(th);
  feats[1] = cosf(th);
  int idx = 2;
  float f = 3.14159265358979323846f;
#pragma unroll
  for (int k = 0; k < 6; k++) {
    feats[idx++] = sinf(f * dx);
    feats[idx++] = cosf(f * dx);
    feats[idx++] = sinf(f * dy);
    feats[idx++] = cosf(f * dy);
    feats[idx++] = sinf(f * th);
    feats[idx++] = cosf(f * th);
    f *= 2.0f;
  }
  __shared__ float hid[64];
  float h = b_edge[tid];
  for (int ff = 0; ff < 38; ff++) h += feats[ff] * W_edge[ff * 64 + tid];
  hid[tid] = h;
  __syncthreads();
#pragma unroll
  for (int i = 0; i < 8; i++) {
    int z = i * 64 + tid;
    float sacc = 0.0f;
    for (int j = 0; j < 64; j++) sacc += hid[j] * We[j * ZDIM + z];
    e[(size_t)bt * ZDIM + z] = sacc;
  }
}

// ---------------- per-d attention over j=8 heads ---------------------------
__global__ __launch_bounds__(256) void attn_kernel(
    const __bf16* __restrict__ q, const __bf16* __restrict__ kc,
    const __bf16* __restrict__ vc, const float* __restrict__ e,
    __bf16* __restrict__ attn_out) {
  int row = blockIdx.x * 4 + (threadIdx.x >> 6); // 0..32767 = bt*A + a
  int lane = threadIdx.x & 63;                   // = d
  int a = row & 511;
  int bt = row >> 9;
  int b = bt >> 4;
  const __bf16* qr = q + (size_t)row * ZDIM;
  const __bf16* kr = kc + ((size_t)b * 512 + a) * ZDIM;
  const __bf16* vr = vc + ((size_t)b * 512 + a) * ZDIM;
  const float* er = e + (size_t)bt * ZDIM;
  float kv[8], vv[8], qv[8];
#pragma unroll
  for (int j = 0; j < 8; j++) {
    kv[j] = (float)kr[j * 64 + lane] + er[j * 64 + lane];
    vv[j] = (float)vr[j * 64 + lane];
  }
#pragma unroll
  for (int i = 0; i < 8; i++) qv[i] = (float)qr[i * 64 + lane];
  const float scale = 0.125f; // 1/sqrt(HD=64)
#pragma unroll
  for (int i = 0; i < 8; i++) {
    float lg[8], m = -1e30f;
#pragma unroll
    for (int j = 0; j < 8; j++) {
      lg[j] = qv[i] * kv[j] * scale;
      m = fmaxf(m, lg[j]);
    }
    float ssum = 0.0f, o = 0.0f;
#pragma unroll
    for (int j = 0; j < 8; j++) {
      float p = __expf(lg[j] - m);
      ssum += p;
      o += p * vv[j];
    }
    attn_out[(size_t)row * ZDIM + i * 64 + lane] = (__bf16)(o / ssum);
  }
}

// ---------------- gate GEMV: g = sigmoid(hg . Wg2 + bg2) -------------------
__global__ __launch_bounds__(256) void gate_kernel(
    const __bf16* __restrict__ hg, const float* __restrict__ Wg2,
    const float* __restrict__ bg2, float* __restrict__ g) {
  int row = blockIdx.x * 4 + (threadIdx.x >> 6);
  int lane = threadIdx.x & 63;
  float s = 0.0f;
#pragma unroll
  for (int i = 0; i < 8; i++) {
    int z = i * 64 + lane;
    s += (float)hg[(size_t)row * ZDIM + z] * Wg2[z];
  }
#pragma unroll
  for (int off = 32; off > 0; off >>= 1) s += __shfl_down(s, off);
  if (lane == 0) g[row] = 1.0f / (1.0f + expf(-(s + bg2[0])));
}

// ---------------- MFMA GEMM: C[M][N] = A[M][K] @ Bt[N][K]^T ----------------
// 128x128 block tile, BK=32, 4 waves (2x2 of 64x64), 16x16x32 bf16 MFMA.
// Staging: bf16x8 register load -> LDS store. bias is f32.
// EPI: 0 = store, 1 = gelu(x + bias), 2 = x + bias + resid(bf16)
template <bool CONCAT, int EPI, typename OT>
__global__ __launch_bounds__(256) void gemm_kernel(
    const __bf16* __restrict__ A1, const __bf16* __restrict__ A2, int ksplit,
    int lda, const __bf16* __restrict__ Bt, const float* __restrict__ bias,
    const __bf16* __restrict__ resid, OT* __restrict__ C, int N, int K) {
  __shared__ __align__(16) __bf16 As[128 * 32];
  __shared__ __align__(16) __bf16 Bs[128 * 32];
  const int tid = threadIdx.x;
  const int wave = tid >> 6, lane = tid & 63;
  const int m0 = blockIdx.x * 128, n0 = blockIdx.y * 128;
  const int srow = lane >> 2;      // staging row within 16-row chunk
  const int scol = (lane & 3) * 8; // staging col (elements)
  const int wm = (wave & 1) * 64, wn = (wave >> 1) * 64;
  const int fr = lane & 15, fq = lane >> 4;

  f32x4 acc[4][4] = {};

  for (int kt = 0; kt < K; kt += 32) {
    const __bf16* Ap;
    int ka;
    if (CONCAT) {
      if (kt < ksplit) { Ap = A1; ka = kt; }
      else             { Ap = A2; ka = kt - ksplit; }
    } else { Ap = A1; ka = kt; }
    bf16x8 va[2], vb[2];
#pragma unroll
    for (int c = 0; c < 2; c++) {
      int r = 32 * wave + 16 * c + srow;
      va[c] = *(const bf16x8*)(Ap + (size_t)(m0 + r) * lda + ka + scol);
      vb[c] = *(const bf16x8*)(Bt + (size_t)(n0 + r) * K + kt + scol);
    }
#pragma unroll
    for (int c = 0; c < 2; c++) {
      int r = 32 * wave + 16 * c + srow;
      *(bf16x8*)&As[r * 32 + scol] = va[c];
      *(bf16x8*)&Bs[r * 32 + scol] = vb[c];
    }
    __syncthreads();
    bf16x8 af[4], bfr[4];
#pragma unroll
    for (int t = 0; t < 4; t++) {
      af[t] = *(const bf16x8*)&As[(wm + t * 16 + fr) * 32 + fq * 8];
      bfr[t] = *(const bf16x8*)&Bs[(wn + t * 16 + fr) * 32 + fq * 8];
    }
#pragma unroll
    for (int mt = 0; mt < 4; mt++)
#pragma unroll
      for (int nt = 0; nt < 4; nt++)
        acc[mt][nt] = __builtin_amdgcn_mfma_f32_16x16x32_bf16(
            af[mt], bfr[nt], acc[mt][nt], 0, 0, 0);
    __syncthreads();
  }

#pragma unroll
  for (int mt = 0; mt < 4; mt++) {
#pragma unroll
    for (int nt = 0; nt < 4; nt++) {
      int col = n0 + wn + nt * 16 + fr;
#pragma unroll
      for (int r = 0; r < 4; r++) {
        int row = m0 + wm + mt * 16 + fq * 4 + r;
        float v = acc[mt][nt][r];
        if (EPI == 1) { v = gelu_f(v + bias[col]); }
        else if (EPI == 2) {
          v += bias[col] + (float)resid[(size_t)row * N + col];
        }
        C[(size_t)row * N + col] = (OT)v;
      }
    }
  }
}

// ---------------------------------------------------------------------------
extern "C" void kernel_launch(void* const* d_in, const int* in_sizes, int n_in,
                              void* d_out, int out_size, void* d_ws,
                              size_t ws_size, hipStream_t stream) {
  const float* z_current = (const float*)d_in[0];
  const float* z_pred = (const float*)d_in[1];
  const float* actions = (const float*)d_in[2];
  const float* Wq = (const float*)d_in[3];
  const float* Wk = (const float*)d_in[4];
  const float* Wv = (const float*)d_in[5];
  const float* We = (const float*)d_in[6];
  const float* Wo = (const float*)d_in[7];
  const float* g_lnq = (const float*)d_in[8];
  const float* b_lnq = (const float*)d_in[9];
  const float* g_lno = (const float*)d_in[10];
  const float* b_lno = (const float*)d_in[11];
  const float* W_ff1 = (const float*)d_in[12];
  const float* b_ff1 = (const float*)d_in[13];
  const float* W_ff2 = (const float*)d_in[14];
  const float* b_ff2 = (const float*)d_in[15];
  const float* W_edge = (const float*)d_in[16];
  const float* b_edge = (const float*)d_in[17];
  const float* Wg1 = (const float*)d_in[18];
  const float* bg1 = (const float*)d_in[19];
  const float* Wg2 = (const float*)d_in[20];
  const float* bg2 = (const float*)d_in[21];

  char* ws = (char*)d_ws;
  size_t off = 0;
  auto alloc = [&](size_t bytes) {
    void* p = ws + off;
    off += (bytes + 255) & ~(size_t)255;
    return p;
  };
  __bf16* WTq = (__bf16*)alloc(512 * 512 * 2);
  __bf16* WTk = (__bf16*)alloc(512 * 512 * 2);
  __bf16* WTv = (__bf16*)alloc(512 * 512 * 2);
  __bf16* WTo = (__bf16*)alloc(512 * 512 * 2);
  __bf16* WTg1 = (__bf16*)alloc(512 * 1024 * 2); // [512][1024]
  __bf16* WTf1 = (__bf16*)alloc(2048 * 512 * 2); // [2048][512]
  __bf16* WTf2 = (__bf16*)alloc(512 * 2048 * 2); // [512][2048]
  __bf16* zc_bf = (__bf16*)alloc(2048 * 512 * 2);
  __bf16* zp_bf = (__bf16*)alloc((size_t)ROWS * ZDIM * 2); // raw z_pred bf16
  __bf16* kc = (__bf16*)alloc(2048 * 512 * 2);
  __bf16* vc = (__bf16*)alloc(2048 * 512 * 2);
  float* ebuf = (float*)alloc(64 * 512 * 4);
  float* gbuf = (float*)alloc(32768 * 4);
  __bf16* BUF_A = (__bf16*)alloc((size_t)ROWS * ZDIM * 2); // lnq -> attn -> h1
  __bf16* BUF_B = (__bf16*)alloc((size_t)ROWS * ZDIM * 2); // q -> out
  __bf16* BUF_C = (__bf16*)alloc((size_t)ROWS * ZDIM * 2); // hg -> zmid
  (void)ws_size; (void)in_sizes; (void)n_in; (void)out_size;

  dim3 tb(32, 8);
  transpose_f32_bf16<<<dim3(16, 16), tb, 0, stream>>>(Wq, WTq, 512, 512);
  transpose_f32_bf16<<<dim3(16, 16), tb, 0, stream>>>(Wk, WTk, 512, 512);
  transpose_f32_bf16<<<dim3(16, 16), tb, 0, stream>>>(Wv, WTv, 512, 512);
  transpose_f32_bf16<<<dim3(16, 16), tb, 0, stream>>>(Wo, WTo, 512, 512);
  transpose_f32_bf16<<<dim3(16, 32), tb, 0, stream>>>(Wg1, WTg1, 1024, 512);
  transpose_f32_bf16<<<dim3(64, 16), tb, 0, stream>>>(W_ff1, WTf1, 512, 2048);
  transpose_f32_bf16<<<dim3(16, 64), tb, 0, stream>>>(W_ff2, WTf2, 2048, 512);

  // z_current -> bf16 (2048*512 = 1,048,576 elems; 4/thread)
  cvt_f32_bf16<<<1024, 256, 0, stream>>>(z_current, zc_bf);
  // lnq = LN(z_pred) -> BUF_A ; raw bf16 z_pred -> zp_bf
  ln_kernel<false, true><<<ROWS, 256, 0, stream>>>(z_pred, nullptr, nullptr,
                                                   g_lnq, b_lnq, BUF_A, zp_bf);
  // e features
  edge_kernel<<<64, 64, 0, stream>>>(actions, W_edge, b_edge, We, ebuf);
  // kc, vc
  gemm_kernel<false, 0, __bf16><<<dim3(16, 4), 256, 0, stream>>>(
      zc_bf, nullptr, 0, 512, WTk, nullptr, nullptr, kc, 512, 512);
  gemm_kernel<false, 0, __bf16><<<dim3(16, 4), 256, 0, stream>>>(
      zc_bf, nullptr, 0, 512, WTv, nullptr, nullptr, vc, 512, 512);
  // q = lnq @ Wq -> BUF_B
  gemm_kernel<false, 0, __bf16><<<dim3(256, 4), 256, 0, stream>>>(
      BUF_A, nullptr, 0, 512, WTq, nullptr, nullptr, BUF_B, 512, 512);
  // attention -> BUF_A
  attn_kernel<<<ROWS / 4, 256, 0, stream>>>(BUF_B, kc, vc, ebuf, BUF_A);
  // out = attn @ Wo -> BUF_B
  gemm_kernel<false, 0, __bf16><<<dim3(256, 4), 256, 0, stream>>>(
      BUF_A, nullptr, 0, 512, WTo, nullptr, nullptr, BUF_B, 512, 512);
  // hg = gelu([out, z_pred] @ Wg1 + bg1) -> BUF_C
  gemm_kernel<true, 1, __bf16><<<dim3(256, 4), 256, 0, stream>>>(
      BUF_B, zp_bf, 512, 512, WTg1, bg1, nullptr, BUF_C, 512, 1024);
  // g = sigmoid(hg . Wg2 + bg2)
  gate_kernel<<<ROWS / 4, 256, 0, stream>>>(BUF_C, Wg2, bg2, gbuf);
  // zmid = LN(z_pred + g*out) -> BUF_C
  ln_kernel<true, false><<<ROWS, 256, 0, stream>>>(z_pred, BUF_B, gbuf, g_lno,
                                                   b_lno, BUF_C, nullptr);
  // FFN chunked over rows (4 x 8192)
  float* outp = (float*)d_out;
  for (int c = 0; c < 4; c++) {
    const __bf16* zmid_c = BUF_C + (size_t)c * 8192 * 512;
    // h1 = gelu(zmid @ Wff1 + b_ff1) -> BUF_A (8192 x 2048)
    gemm_kernel<false, 1, __bf16><<<dim3(64, 16), 256, 0, stream>>>(
        zmid_c, nullptr, 0, 512, WTf1, b_ff1, nullptr, BUF_A, 2048, 512);
    // y = zmid + h1 @ Wff2 + b_ff2 -> d_out (f32)
    gemm_kernel<false, 2, float><<<dim3(64, 4), 256, 0, stream>>>(
        BUF_A, nullptr, 0, 2048, WTf2, b_ff2, zmid_c,
        outp + (size_t)c * 8192 * 512, 512, 2048);
  }
}

// Round 4
// 679.087 us; speedup vs baseline: 1.2064x; 1.2064x over previous
//
#include <hip/hip_runtime.h>
#include <hip/hip_bf16.h>
#include <math.h>

// PsiForesight fused pipeline for MI355X (gfx950).
// B=4, T=16, A=512, Z=512, E=64, H=8, HD=64, NF=6. Rows = B*T*A = 32768.
//
// R4: (1) async global->LDS staging (global_load_lds width=16, proper
//     addrspacecast — R1's uintptr_t round-trip was inttoptr, the NaN bug);
//     (2) kc/vc merged into one GEMM (kvc, row stride 1024);
//     (3) FFN in 2 chunks (h1 reuses BUF_A+BUF_B).

typedef __bf16 bf16x8 __attribute__((ext_vector_type(8)));
typedef float f32x4 __attribute__((ext_vector_type(4)));

#define ROWS 32768
#define ZDIM 512

__device__ __forceinline__ void gload16(const void* gptr, void* ldsptr) {
  __builtin_amdgcn_global_load_lds(
      (const __attribute__((address_space(1))) unsigned int*)gptr,
      (__attribute__((address_space(3))) unsigned int*)ldsptr, 16, 0, 0);
}

__device__ __forceinline__ float gelu_f(float x) {
  return 0.5f * x * (1.0f + erff(x * 0.70710678118654752f));
}

// ---------------- f32 -> bf16 transpose: out[C][R] = in[R][C] --------------
__global__ void transpose_f32_bf16(const float* __restrict__ in,
                                   __bf16* __restrict__ out, int R, int C) {
  __shared__ float tile[32][33];
  int c0 = blockIdx.x * 32, r0 = blockIdx.y * 32;
#pragma unroll
  for (int i = 0; i < 32; i += 8)
    tile[i + threadIdx.y][threadIdx.x] =
        in[(size_t)(r0 + i + threadIdx.y) * C + c0 + threadIdx.x];
  __syncthreads();
#pragma unroll
  for (int i = 0; i < 32; i += 8)
    out[(size_t)(c0 + i + threadIdx.y) * R + r0 + threadIdx.x] =
        (__bf16)tile[threadIdx.x][i + threadIdx.y];
}

// ---------------- f32 -> bf16 convert (n % 1024 == 0) ----------------------
__global__ void cvt_f32_bf16(const float* __restrict__ in,
                             __bf16* __restrict__ out) {
  int i = (blockIdx.x * 256 + threadIdx.x) * 4;
  float4 v = *(const float4*)(in + i);
  out[i + 0] = (__bf16)v.x;
  out[i + 1] = (__bf16)v.y;
  out[i + 2] = (__bf16)v.z;
  out[i + 3] = (__bf16)v.w;
}

// ---------------- LayerNorm rows (optionally x = a + gate*b) ----------------
template <bool GATED, bool EMIT_RAW>
__global__ __launch_bounds__(256) void ln_kernel(
    const float* __restrict__ xa, const __bf16* __restrict__ xb,
    const float* __restrict__ gate, const float* __restrict__ gamma,
    const float* __restrict__ beta, __bf16* __restrict__ out,
    __bf16* __restrict__ raw) {
  int row = blockIdx.x;
  int tid = threadIdx.x;
  int i0 = tid * 2;
  const float* ra = xa + (size_t)row * ZDIM;
  float x0 = ra[i0], x1 = ra[i0 + 1];
  if (EMIT_RAW) {
    raw[(size_t)row * ZDIM + i0] = (__bf16)x0;
    raw[(size_t)row * ZDIM + i0 + 1] = (__bf16)x1;
  }
  if (GATED) {
    float gv = gate[row];
    const __bf16* rb = xb + (size_t)row * ZDIM;
    x0 += gv * (float)rb[i0];
    x1 += gv * (float)rb[i0 + 1];
  }
  float s = x0 + x1, s2 = x0 * x0 + x1 * x1;
#pragma unroll
  for (int off = 32; off > 0; off >>= 1) {
    s += __shfl_down(s, off);
    s2 += __shfl_down(s2, off);
  }
  __shared__ float red[8];
  int wave = tid >> 6, lane = tid & 63;
  if (lane == 0) { red[wave] = s; red[4 + wave] = s2; }
  __syncthreads();
  float ts = red[0] + red[1] + red[2] + red[3];
  float ts2 = red[4] + red[5] + red[6] + red[7];
  float mean = ts * (1.0f / ZDIM);
  float var = ts2 * (1.0f / ZDIM) - mean * mean;
  float rstd = rsqrtf(var + 1e-5f);
  float y0 = (x0 - mean) * rstd * gamma[i0] + beta[i0];
  float y1 = (x1 - mean) * rstd * gamma[i0 + 1] + beta[i0 + 1];
  out[(size_t)row * ZDIM + i0] = (__bf16)y0;
  out[(size_t)row * ZDIM + i0 + 1] = (__bf16)y1;
}

// ---------------- edge features: e[bt][512] (all f32) ----------------------
__global__ void edge_kernel(const float* __restrict__ actions,
                            const float* __restrict__ W_edge,
                            const float* __restrict__ b_edge,
                            const float* __restrict__ We,
                            float* __restrict__ e) {
  int bt = blockIdx.x;   // 0..63
  int tid = threadIdx.x; // 0..63
  float dx = actions[bt * 4 + 0];
  float dy = actions[bt * 4 + 1];
  float th = actions[bt * 4 + 2];
  float feats[38];
  feats[0] = sinf(th);
  feats[1] = cosf(th);
  int idx = 2;
  float f = 3.14159265358979323846f;
#pragma unroll
  for (int k = 0; k < 6; k++) {
    feats[idx++] = sinf(f * dx);
    feats[idx++] = cosf(f * dx);
    feats[idx++] = sinf(f * dy);
    feats[idx++] = cosf(f * dy);
    feats[idx++] = sinf(f * th);
    feats[idx++] = cosf(f * th);
    f *= 2.0f;
  }
  __shared__ float hid[64];
  float h = b_edge[tid];
  for (int ff = 0; ff < 38; ff++) h += feats[ff] * W_edge[ff * 64 + tid];
  hid[tid] = h;
  __syncthreads();
#pragma unroll
  for (int i = 0; i < 8; i++) {
    int z = i * 64 + tid;
    float sacc = 0.0f;
    for (int j = 0; j < 64; j++) sacc += hid[j] * We[j * ZDIM + z];
    e[(size_t)bt * ZDIM + z] = sacc;
  }
}

// ---------------- per-d attention over j=8 heads ---------------------------
// kvc: [b*512+a][1024]; cols 0..511 = kc, 512..1023 = vc.
__global__ __launch_bounds__(256) void attn_kernel(
    const __bf16* __restrict__ q, const __bf16* __restrict__ kvc,
    const float* __restrict__ e, __bf16* __restrict__ attn_out) {
  int row = blockIdx.x * 4 + (threadIdx.x >> 6); // 0..32767 = bt*A + a
  int lane = threadIdx.x & 63;                   // = d
  int a = row & 511;
  int bt = row >> 9;
  int b = bt >> 4;
  const __bf16* qr = q + (size_t)row * ZDIM;
  const __bf16* kr = kvc + ((size_t)b * 512 + a) * 1024;
  const __bf16* vr = kr + 512;
  const float* er = e + (size_t)bt * ZDIM;
  float kv[8], vv[8], qv[8];
#pragma unroll
  for (int j = 0; j < 8; j++) {
    kv[j] = (float)kr[j * 64 + lane] + er[j * 64 + lane];
    vv[j] = (float)vr[j * 64 + lane];
  }
#pragma unroll
  for (int i = 0; i < 8; i++) qv[i] = (float)qr[i * 64 + lane];
  const float scale = 0.125f; // 1/sqrt(HD=64)
#pragma unroll
  for (int i = 0; i < 8; i++) {
    float lg[8], m = -1e30f;
#pragma unroll
    for (int j = 0; j < 8; j++) {
      lg[j] = qv[i] * kv[j] * scale;
      m = fmaxf(m, lg[j]);
    }
    float ssum = 0.0f, o = 0.0f;
#pragma unroll
    for (int j = 0; j < 8; j++) {
      float p = __expf(lg[j] - m);
      ssum += p;
      o += p * vv[j];
    }
    attn_out[(size_t)row * ZDIM + i * 64 + lane] = (__bf16)(o / ssum);
  }
}

// ---------------- gate GEMV: g = sigmoid(hg . Wg2 + bg2) -------------------
__global__ __launch_bounds__(256) void gate_kernel(
    const __bf16* __restrict__ hg, const float* __restrict__ Wg2,
    const float* __restrict__ bg2, float* __restrict__ g) {
  int row = blockIdx.x * 4 + (threadIdx.x >> 6);
  int lane = threadIdx.x & 63;
  float s = 0.0f;
#pragma unroll
  for (int i = 0; i < 8; i++) {
    int z = i * 64 + lane;
    s += (float)hg[(size_t)row * ZDIM + z] * Wg2[z];
  }
#pragma unroll
  for (int off = 32; off > 0; off >>= 1) s += __shfl_down(s, off);
  if (lane == 0) g[row] = 1.0f / (1.0f + expf(-(s + bg2[0])));
}

// ---------------- MFMA GEMM: C[M][N] = A[M][K] @ Bt[N][K]^T ----------------
// 128x128 block tile, BK=32, 4 waves (2x2 of 64x64), 16x16x32 bf16 MFMA.
// Staging: global_load_lds width=16 (async DMA). LDS dest per chunk is
// wave-uniform base + lane*16B (layout satisfies the contiguity rule).
// EPI: 0 = store, 1 = gelu(x + bias), 2 = x + bias + resid(bf16)
template <bool CONCAT, int EPI, typename OT>
__global__ __launch_bounds__(256) void gemm_kernel(
    const __bf16* __restrict__ A1, const __bf16* __restrict__ A2, int ksplit,
    int lda, const __bf16* __restrict__ Bt, const float* __restrict__ bias,
    const __bf16* __restrict__ resid, OT* __restrict__ C, int N, int K) {
  __shared__ __align__(16) __bf16 As[128 * 32];
  __shared__ __align__(16) __bf16 Bs[128 * 32];
  const int tid = threadIdx.x;
  const int wave = tid >> 6, lane = tid & 63;
  const int m0 = blockIdx.x * 128, n0 = blockIdx.y * 128;
  const int srow = lane >> 2;      // staging row within 16-row chunk
  const int scol = (lane & 3) * 8; // staging col (elements)
  const int wm = (wave & 1) * 64, wn = (wave >> 1) * 64;
  const int fr = lane & 15, fq = lane >> 4;

  f32x4 acc[4][4] = {};

  for (int kt = 0; kt < K; kt += 32) {
    const __bf16* Ap;
    int ka;
    if (CONCAT) {
      if (kt < ksplit) { Ap = A1; ka = kt; }
      else             { Ap = A2; ka = kt - ksplit; }
    } else { Ap = A1; ka = kt; }
#pragma unroll
    for (int c = 0; c < 2; c++) {
      int r = 32 * wave + 16 * c + srow;
      gload16(Ap + (size_t)(m0 + r) * lda + ka + scol,
              &As[(32 * wave + 16 * c) * 32]);
      gload16(Bt + (size_t)(n0 + r) * K + kt + scol,
              &Bs[(32 * wave + 16 * c) * 32]);
    }
    __syncthreads();
    bf16x8 af[4], bfr[4];
#pragma unroll
    for (int t = 0; t < 4; t++) {
      af[t] = *(const bf16x8*)&As[(wm + t * 16 + fr) * 32 + fq * 8];
      bfr[t] = *(const bf16x8*)&Bs[(wn + t * 16 + fr) * 32 + fq * 8];
    }
#pragma unroll
    for (int mt = 0; mt < 4; mt++)
#pragma unroll
      for (int nt = 0; nt < 4; nt++)
        acc[mt][nt] = __builtin_amdgcn_mfma_f32_16x16x32_bf16(
            af[mt], bfr[nt], acc[mt][nt], 0, 0, 0);
    __syncthreads();
  }

#pragma unroll
  for (int mt = 0; mt < 4; mt++) {
#pragma unroll
    for (int nt = 0; nt < 4; nt++) {
      int col = n0 + wn + nt * 16 + fr;
#pragma unroll
      for (int r = 0; r < 4; r++) {
        int row = m0 + wm + mt * 16 + fq * 4 + r;
        float v = acc[mt][nt][r];
        if (EPI == 1) { v = gelu_f(v + bias[col]); }
        else if (EPI == 2) {
          v += bias[col] + (float)resid[(size_t)row * N + col];
        }
        C[(size_t)row * N + col] = (OT)v;
      }
    }
  }
}

// ---------------------------------------------------------------------------
extern "C" void kernel_launch(void* const* d_in, const int* in_sizes, int n_in,
                              void* d_out, int out_size, void* d_ws,
                              size_t ws_size, hipStream_t stream) {
  const float* z_current = (const float*)d_in[0];
  const float* z_pred = (const float*)d_in[1];
  const float* actions = (const float*)d_in[2];
  const float* Wq = (const float*)d_in[3];
  const float* Wk = (const float*)d_in[4];
  const float* Wv = (const float*)d_in[5];
  const float* We = (const float*)d_in[6];
  const float* Wo = (const float*)d_in[7];
  const float* g_lnq = (const float*)d_in[8];
  const float* b_lnq = (const float*)d_in[9];
  const float* g_lno = (const float*)d_in[10];
  const float* b_lno = (const float*)d_in[11];
  const float* W_ff1 = (const float*)d_in[12];
  const float* b_ff1 = (const float*)d_in[13];
  const float* W_ff2 = (const float*)d_in[14];
  const float* b_ff2 = (const float*)d_in[15];
  const float* W_edge = (const float*)d_in[16];
  const float* b_edge = (const float*)d_in[17];
  const float* Wg1 = (const float*)d_in[18];
  const float* bg1 = (const float*)d_in[19];
  const float* Wg2 = (const float*)d_in[20];
  const float* bg2 = (const float*)d_in[21];

  char* ws = (char*)d_ws;
  size_t off = 0;
  auto alloc = [&](size_t bytes) {
    void* p = ws + off;
    off += (bytes + 255) & ~(size_t)255;
    return p;
  };
  __bf16* WTkv = (__bf16*)alloc(1024 * 512 * 2); // [0:512)=Wk^T, [512:1024)=Wv^T
  __bf16* WTq = (__bf16*)alloc(512 * 512 * 2);
  __bf16* WTo = (__bf16*)alloc(512 * 512 * 2);
  __bf16* WTg1 = (__bf16*)alloc(512 * 1024 * 2); // [512][1024]
  __bf16* WTf1 = (__bf16*)alloc(2048 * 512 * 2); // [2048][512]
  __bf16* WTf2 = (__bf16*)alloc(512 * 2048 * 2); // [512][2048]
  __bf16* zc_bf = (__bf16*)alloc(2048 * 512 * 2);
  __bf16* zp_bf = (__bf16*)alloc((size_t)ROWS * ZDIM * 2); // raw z_pred bf16
  __bf16* kvc = (__bf16*)alloc(2048 * 1024 * 2);           // fused k|v
  float* ebuf = (float*)alloc(64 * 512 * 4);
  float* gbuf = (float*)alloc(32768 * 4);
  // BUF_A and BUF_B deliberately contiguous: reused as one 16384x2048 h1 buf.
  __bf16* BUF_A = (__bf16*)alloc((size_t)2 * ROWS * ZDIM * 2);
  __bf16* BUF_B = BUF_A + (size_t)ROWS * ZDIM;
  __bf16* BUF_C = (__bf16*)alloc((size_t)ROWS * ZDIM * 2); // hg -> zmid
  (void)ws_size; (void)in_sizes; (void)n_in; (void)out_size;

  dim3 tb(32, 8);
  transpose_f32_bf16<<<dim3(16, 16), tb, 0, stream>>>(Wk, WTkv, 512, 512);
  transpose_f32_bf16<<<dim3(16, 16), tb, 0, stream>>>(Wv, WTkv + 512 * 512,
                                                      512, 512);
  transpose_f32_bf16<<<dim3(16, 16), tb, 0, stream>>>(Wq, WTq, 512, 512);
  transpose_f32_bf16<<<dim3(16, 16), tb, 0, stream>>>(Wo, WTo, 512, 512);
  transpose_f32_bf16<<<dim3(16, 32), tb, 0, stream>>>(Wg1, WTg1, 1024, 512);
  transpose_f32_bf16<<<dim3(64, 16), tb, 0, stream>>>(W_ff1, WTf1, 512, 2048);
  transpose_f32_bf16<<<dim3(16, 64), tb, 0, stream>>>(W_ff2, WTf2, 2048, 512);

  // z_current -> bf16 (2048*512 elems, 4/thread)
  cvt_f32_bf16<<<1024, 256, 0, stream>>>(z_current, zc_bf);
  // lnq = LN(z_pred) -> BUF_A ; raw bf16 z_pred -> zp_bf
  ln_kernel<false, true><<<ROWS, 256, 0, stream>>>(z_pred, nullptr, nullptr,
                                                   g_lnq, b_lnq, BUF_A, zp_bf);
  // e features
  edge_kernel<<<64, 64, 0, stream>>>(actions, W_edge, b_edge, We, ebuf);
  // kvc = z_current @ [Wk | Wv]  (M=2048, N=1024, K=512)
  gemm_kernel<false, 0, __bf16><<<dim3(16, 8), 256, 0, stream>>>(
      zc_bf, nullptr, 0, 512, WTkv, nullptr, nullptr, kvc, 1024, 512);
  // q = lnq @ Wq -> BUF_B
  gemm_kernel<false, 0, __bf16><<<dim3(256, 4), 256, 0, stream>>>(
      BUF_A, nullptr, 0, 512, WTq, nullptr, nullptr, BUF_B, 512, 512);
  // attention -> BUF_A
  attn_kernel<<<ROWS / 4, 256, 0, stream>>>(BUF_B, kvc, ebuf, BUF_A);
  // out = attn @ Wo -> BUF_B
  gemm_kernel<false, 0, __bf16><<<dim3(256, 4), 256, 0, stream>>>(
      BUF_A, nullptr, 0, 512, WTo, nullptr, nullptr, BUF_B, 512, 512);
  // hg = gelu([out, z_pred] @ Wg1 + bg1) -> BUF_C  (M=32768, N=512, K=1024)
  gemm_kernel<true, 1, __bf16><<<dim3(256, 4), 256, 0, stream>>>(
      BUF_B, zp_bf, 512, 512, WTg1, bg1, nullptr, BUF_C, 512, 1024);
  // g = sigmoid(hg . Wg2 + bg2)
  gate_kernel<<<ROWS / 4, 256, 0, stream>>>(BUF_C, Wg2, bg2, gbuf);
  // zmid = LN(z_pred + g*out) -> BUF_C
  ln_kernel<true, false><<<ROWS, 256, 0, stream>>>(z_pred, BUF_B, gbuf, g_lno,
                                                   b_lno, BUF_C, nullptr);
  // FFN in 2 chunks of 16384 rows; h1 (16384x2048 bf16, 67MB) = BUF_A+BUF_B
  float* outp = (float*)d_out;
  __bf16* h1 = BUF_A;
  for (int c = 0; c < 2; c++) {
    const __bf16* zmid_c = BUF_C + (size_t)c * 16384 * 512;
    gemm_kernel<false, 1, __bf16><<<dim3(128, 16), 256, 0, stream>>>(
        zmid_c, nullptr, 0, 512, WTf1, b_ff1, nullptr, h1, 2048, 512);
    gemm_kernel<false, 2, float><<<dim3(128, 4), 256, 0, stream>>>(
        h1, nullptr, 0, 2048, WTf2, b_ff2, zmid_c,
        outp + (size_t)c * 16384 * 512, 512, 2048);
  }
}